// Round 16
// baseline (1320.312 us; speedup 1.0000x reference)
//
#include <hip/hip_runtime.h>
#include <cstdint>
#include <cstddef>

// ---------------------------------------------------------------------------
// PointNet++ SA module (multi-scale grouping) with attention gate.
// B=16, N=4096, C_IN=64, NPOINT=1024, radii (0.2,0.4), nsamples (32,64),
// MLPs ((64,64,128),(64,64,128)), C_TOTAL=256. Inputs f32, output f32.
// Round 25: K3 back to the r18 128-col form (tile curve flat past 128:
// r23 1279 @128col/4waves == r24 1281 @256col/2waves -> neither overhead
// nor TLP is binding; the stall is in-loop LATENCY) + w2 staged in LDS:
// the L3 k-loop's 2 global weight loads/k (L2-hit ~200cyc, marginally
// covered by unroll-2) become ds_read_b128. LDS 33.8->65KB, 2 blocks/CU
// (r24: 2 waves/SIMD costs nothing). Staging is a verbatim copy; FMA order
// unchanged -> bit-exact. w1 stays global (80KB budget) and keeps the
// memory pipe warm. K1 frozen r21 (587us), g1 r23, K2 r9.
// ---------------------------------------------------------------------------

constexpr int B_ = 16, N_ = 4096, S_ = 1024;
constexpr int WT_G = 67*64 + 64*64 + 128*64 + 64 + 64 + 128; // 16832 floats/group
constexpr int FPS_T = 512;                                   // threads per FPS block
constexpr int WT_BLK = (2*WT_G + FPS_T - 1) / FPS_T;         // 66
constexpr int G1_BLK = 2 * B_ * (N_ / 128);                  // 1024

// workspace layout in 4-byte units
constexpr int WS_XYZF = 0;                       // float4[B*N]
constexpr int WS_NXYZ = B_*N_*4;                 // float[B*S*3]
constexpr int WS_ATT  = WS_NXYZ + B_*S_*3;       // float[B*256]
constexpr int WS_WT   = WS_ATT + B_*256;         // float[2*WT_G]
constexpr int WS_IDX0 = WS_WT + 2*WT_G;          // int[B*S*32]
constexpr int WS_IDX1 = WS_IDX0 + B_*S_*32;      // int[B*S*64]
constexpr int WS_F1   = WS_IDX1 + B_*S_*64;      // float[2*B*N*64] G1 values

// ---------------------------------------------------------------------------
// K0: G1 precompute (r23). Per point p: G1[o] = sum_c w0[o,c]*in[c].
// 1024 blocks x 256 thr; 2 threads/point, 32 outs each (4 waves/SIMD).
// ---------------------------------------------------------------------------
__global__ __launch_bounds__(256) void g1_kernel(
    const float* __restrict__ xyz, const float* __restrict__ feats,
    const float* __restrict__ w00, const float* __restrict__ w10,
    float* __restrict__ f1) {
  __shared__ float wfs[67 * 64];   // wfs[c*64+o] = w[o*67+c]
  const int fid = blockIdx.x;                     // 0..1023
  const int g = fid >> 9, b = (fid >> 5) & 15, chunk = fid & 31;
  const float* w = g ? w10 : w00;
  for (int k = threadIdx.x; k < 67*64; k += 256) {
    int c = k >> 6, o = k & 63;
    wfs[k] = w[o*67 + c];
  }
  __syncthreads();
  const int p = chunk * 128 + (threadIdx.x >> 1);
  const int half = (threadIdx.x & 1) * 32;        // output half: o = half..half+31
  const float* xr = xyz + ((size_t)b * N_ + p) * 3;
  const float* fr = feats + ((size_t)b * N_ + p) * 64;
  float acc[32];
  {
    float x0 = xr[0], x1 = xr[1], x2 = xr[2];
#pragma unroll
    for (int j = 0; j < 32; j += 4) {
      float4 wA = *(const float4*)&wfs[0*64 + half + j];
      acc[j+0] = wA.x * x0; acc[j+1] = wA.y * x0;
      acc[j+2] = wA.z * x0; acc[j+3] = wA.w * x0;
    }
#pragma unroll
    for (int j = 0; j < 32; j += 4) {
      float4 wA = *(const float4*)&wfs[1*64 + half + j];
      acc[j+0] = fmaf(wA.x, x1, acc[j+0]); acc[j+1] = fmaf(wA.y, x1, acc[j+1]);
      acc[j+2] = fmaf(wA.z, x1, acc[j+2]); acc[j+3] = fmaf(wA.w, x1, acc[j+3]);
    }
#pragma unroll
    for (int j = 0; j < 32; j += 4) {
      float4 wA = *(const float4*)&wfs[2*64 + half + j];
      acc[j+0] = fmaf(wA.x, x2, acc[j+0]); acc[j+1] = fmaf(wA.y, x2, acc[j+1]);
      acc[j+2] = fmaf(wA.z, x2, acc[j+2]); acc[j+3] = fmaf(wA.w, x2, acc[j+3]);
    }
  }
  for (int c = 0; c < 64; ++c) {
    float v = fr[c];
    const float* wr = &wfs[(3 + c) * 64 + half];
#pragma unroll
    for (int j = 0; j < 32; j += 4) {
      float4 w4 = *(const float4*)&wr[j];
      acc[j+0] = fmaf(w4.x, v, acc[j+0]); acc[j+1] = fmaf(w4.y, v, acc[j+1]);
      acc[j+2] = fmaf(w4.z, v, acc[j+2]); acc[j+3] = fmaf(w4.w, v, acc[j+3]);
    }
  }
  float* op = f1 + (((size_t)g * B_ + b) * N_ + p) * 64 + half;
#pragma unroll
  for (int j = 0; j < 32; j += 4) {
    float4 r = make_float4(acc[j], acc[j+1], acc[j+2], acc[j+3]);
    *(float4*)&op[j] = r;
  }
}

// ---------------------------------------------------------------------------
// K1: FPS (blocks 0..15, 512 thr / 8 waves / PPT=8) + weight transpose
// (blocks 16..81). Byte-identical to r21 (587 us measured).
// ---------------------------------------------------------------------------
__global__ __launch_bounds__(512) void fps_wt_kernel(
    const float* __restrict__ xyz,
    const float* __restrict__ w00, const float* __restrict__ w01,
    const float* __restrict__ w02, const float* __restrict__ b00,
    const float* __restrict__ b01, const float* __restrict__ b02,
    const float* __restrict__ w10, const float* __restrict__ w11,
    const float* __restrict__ w12, const float* __restrict__ b10,
    const float* __restrict__ b11, const float* __restrict__ b12,
    float4* __restrict__ xyzf, float* __restrict__ wt,
    float* __restrict__ nxyz, float* __restrict__ out_nxyz) {
  constexpr int PPT = 8;           // points per thread (4096 / 512)
  __shared__ float sx[N_*3];
  __shared__ int   selidx[S_];
  __shared__ alignas(16) unsigned long long redP[2][8];

  if (blockIdx.x >= B_) {
    // ---- weight-transpose role (runs on idle CUs during FPS) ----
    int wid = (blockIdx.x - B_) * FPS_T + threadIdx.x;
    if (wid >= 2*WT_G) return;
    int g = wid / WT_G, r = wid % WT_G;
    float val;
    if (r < 4288) {                    // layer0: w (64,67) -> wt0[c*64+o]
      int c = r >> 6, o = r & 63;
      val = (g ? w10 : w00)[o*67 + c];
    } else if (r < 8384) {             // layer1: w (64,64) -> wt1[c*64+o]
      int rr = r - 4288; int c = rr >> 6, o = rr & 63;
      val = (g ? w11 : w01)[o*64 + c];
    } else if (r < 16576) {            // layer2: w (128,64) -> wt2[c*128+o]
      int rr = r - 8384; int c = rr >> 7, o = rr & 127;
      val = (g ? w12 : w02)[o*64 + c];
    } else {                           // biases
      int rr = r - 16576;
      val = (rr < 64)  ? (g ? b10 : b00)[rr]
          : (rr < 128) ? (g ? b11 : b01)[rr - 64]
                       : (g ? b12 : b02)[rr - 128];
    }
    wt[g*WT_G + r] = val;
    return;
  }

  // ---- FPS role ----
  const int b = blockIdx.x, t = threadIdx.x;
  const int wv = t >> 6;  // wave id 0..7
  const float* xr = xyz + (size_t)b * N_ * 3;
  for (int k = t; k < N_*3; k += FPS_T) sx[k] = xr[k];   // coalesced stage
  if (t == 0) selidx[0] = 0;   // first sampled index is 0 (matches reference)
  __syncthreads();
  float px[PPT], py[PPT], pz[PPT], m[PPT];
#pragma unroll
  for (int p = 0; p < PPT; ++p) {
    int idx = t * PPT + p;
    px[p] = sx[idx*3+0]; py[p] = sx[idx*3+1]; pz[p] = sx[idx*3+2];
    m[p] = 1e10f;
  }
  float lx = sx[0], ly = sx[1], lz = sx[2];
  for (int i = 1; i < S_; ++i) {
    // ---- distance + running-min update (bit-exact np arithmetic) ----
#pragma unroll
    for (int p = 0; p < PPT; ++p) {
      float dx = __fsub_rn(px[p], lx), dy = __fsub_rn(py[p], ly), dz = __fsub_rn(pz[p], lz);
      float d = __fadd_rn(__fadd_rn(__fmul_rn(dx,dx), __fmul_rn(dy,dy)), __fmul_rn(dz,dz));
      m[p] = fminf(m[p], d);
    }
    // ---- local argmax: max tree + reverse == scan (smallest p wins) ----
    float h0 = fmaxf(fmaxf(m[0], m[1]), fmaxf(m[2], m[3]));
    float h1 = fmaxf(fmaxf(m[4], m[5]), fmaxf(m[6], m[7]));
    float bv = fmaxf(h0, h1);
    int bp = PPT - 1;
#pragma unroll
    for (int p = PPT - 2; p >= 0; --p)
      if (m[p] == bv) bp = p;           // ends at smallest p attaining bv
    const int bi = t * PPT + bp;
    // ---- wave max via DPP (uint compare valid: all m >= 0, no NaN) ----
    unsigned vm = __float_as_uint(bv);
#define DPP_MAX(ctrl) { unsigned o = (unsigned)__builtin_amdgcn_update_dpp((int)vm, (int)vm, (ctrl), 0xf, 0xf, false); vm = vm > o ? vm : o; }
    DPP_MAX(0x111)  // row_shr:1
    DPP_MAX(0x112)  // row_shr:2
    DPP_MAX(0x114)  // row_shr:4
    DPP_MAX(0x118)  // row_shr:8
    DPP_MAX(0x142)  // row_bcast:15
    DPP_MAX(0x143)  // row_bcast:31
#undef DPP_MAX
    const unsigned wmaxu = (unsigned)__builtin_amdgcn_readlane((int)vm, 63);
    // smallest index attaining the wave max: lanes are index-ordered
    const unsigned long long mk = __ballot(__float_as_uint(bv) == wmaxu);
    const int fl = (int)__builtin_ctzll(mk);
    const int widx = __builtin_amdgcn_readlane(bi, fl);
    const int par = i & 1;
    // ---- winner lane forwards packed key ONLY (no coord select/write) ----
    if (t == (widx >> 3))
      redP[par][wv] = ((unsigned long long)wmaxu << 32) | (unsigned)(~widx);
    __syncthreads();
    // ---- all threads: combine 8 wave candidates (broadcast LDS reads),
    //      then fetch winner coords straight from sx (uniform broadcast) ----
    ulonglong2 pA = *(const ulonglong2*)&redP[par][0];
    ulonglong2 pB = *(const ulonglong2*)&redP[par][2];
    ulonglong2 pC = *(const ulonglong2*)&redP[par][4];
    ulonglong2 pD = *(const ulonglong2*)&redP[par][6];
    unsigned long long q0 = pA.x > pA.y ? pA.x : pA.y;
    unsigned long long q1 = pB.x > pB.y ? pB.x : pB.y;
    unsigned long long q2 = pC.x > pC.y ? pC.x : pC.y;
    unsigned long long q3 = pD.x > pD.y ? pD.x : pD.y;
    unsigned long long r0 = q0 > q1 ? q0 : q1;
    unsigned long long r1 = q2 > q3 ? q2 : q3;
    unsigned long long win = r0 > r1 ? r0 : r1;
    const int fi = (int)(~(unsigned)win);   // global index of selected point
    lx = sx[fi*3+0]; ly = sx[fi*3+1]; lz = sx[fi*3+2];  // broadcast reads
    if (t == 0) selidx[i] = fi;
  }
  __syncthreads();
  // epilogue: coalesced write of new_xyz (ws + out) and xyzf (float4-padded)
  for (int k = t; k < S_; k += FPS_T) {
    int id = selidx[k];
    float x = sx[id*3], y = sx[id*3+1], z = sx[id*3+2];
    int o = (b * S_ + k) * 3;
    nxyz[o] = x; nxyz[o+1] = y; nxyz[o+2] = z;
    out_nxyz[o] = x; out_nxyz[o+1] = y; out_nxyz[o+2] = z;
  }
  for (int k = t; k < N_; k += FPS_T) {
    float4 v; v.x = sx[k*3]; v.y = sx[k*3+1]; v.z = sx[k*3+2]; v.w = 0.f;
    xyzf[b * N_ + k] = v;
  }
}

// ---------------------------------------------------------------------------
// K2: fused dual-radius ball query (blocks 0..4095) + attention gate
// (blocks 4096..4111). Byte-identical to round 9.
// ---------------------------------------------------------------------------
__global__ __launch_bounds__(256) void ballq_att_kernel(
    const float4* __restrict__ xyzf, const float* __restrict__ nxyz,
    int* __restrict__ idx0buf, int* __restrict__ idx1buf,
    const float* __restrict__ w_att, const float* __restrict__ b_att,
    float* __restrict__ att) {
  __shared__ float ai[3 * S_];
  if (blockIdx.x >= B_*S_/4) {
    // ---- attention role ----
    int b = blockIdx.x - B_*S_/4, t = threadIdx.x;
    for (int k = t; k < 3 * S_; k += 256) {
      int d = k >> 10, s = k & 1023;
      ai[k] = nxyz[(b * S_ + s) * 3 + d];
    }
    __syncthreads();
    float acc = b_att[t];
#pragma unroll 8
    for (int k = 0; k < 3 * S_; ++k)
      acc = fmaf(ai[k], w_att[k * 256 + t], acc);
    att[b * 256 + t] = 1.f / (1.f + expf(-acc));
    return;
  }
  // ---- ball-query role ----
  const float r2a = (float)(0.2 * 0.2), r2b = (float)(0.4 * 0.4);
  int lane = threadIdx.x & 63;
  int cid = blockIdx.x * 4 + (threadIdx.x >> 6);
  int b = cid >> 10;
  float cx = nxyz[cid*3], cy = nxyz[cid*3+1], cz = nxyz[cid*3+2];
  const float4* xb = xyzf + b * N_;
  int cnt0 = 0, cnt1 = 0, first0 = 0, first1 = 0;
  const unsigned long long below = (1ull << lane) - 1ull;
  for (int base = 0; base < N_; base += 64) {
    float4 P = xb[base + lane];
    float dx = __fsub_rn(cx, P.x), dy = __fsub_rn(cy, P.y), dz = __fsub_rn(cz, P.z);
    float d2 = __fadd_rn(__fadd_rn(__fmul_rn(dx,dx), __fmul_rn(dy,dy)), __fmul_rn(dz,dz));
    bool h0 = d2 < r2a, h1 = d2 < r2b;
    unsigned long long m0 = __ballot(h0), m1 = __ballot(h1);
    if (cnt0 == 0 && m0 != 0ull) first0 = base + (int)__builtin_ctzll(m0);
    if (cnt1 == 0 && m1 != 0ull) first1 = base + (int)__builtin_ctzll(m1);
    if (h0) {
      int pos = cnt0 + (int)__popcll(m0 & below);
      if (pos < 32) idx0buf[cid * 32 + pos] = base + lane;
    }
    if (h1) {
      int pos = cnt1 + (int)__popcll(m1 & below);
      if (pos < 64) idx1buf[cid * 64 + pos] = base + lane;
    }
    cnt0 += (int)__popcll(m0);
    cnt1 += (int)__popcll(m1);
    if (cnt0 >= 32 && cnt1 >= 64) break;
  }
  if (cnt0 < 32)
    for (int p = cnt0 + lane; p < 32; p += 64) idx0buf[cid * 32 + p] = first0;
  if (cnt1 < 64)
    for (int p = cnt1 + lane; p < 64; p += 64) idx1buf[cid * 64 + p] = first1;
}

// ---------------------------------------------------------------------------
// K3: GEMM-tiled fused MLP + maxpool + attention + store. r18 128-col form
// + w2 staged in LDS (verbatim copy at block start, ordered by the L1->L2
// barrier; L3 weight loads become ds_read_b128). Scalar fmaf, unroll-2
// k-loops, identical per-col chain order -> bit-exact.
// ---------------------------------------------------------------------------
template<int NS>
__device__ __forceinline__ void mlp_body(int bi, float* xs, float* w2s,
    const float* __restrict__ f1g,
    const float* __restrict__ nxyz, const float* __restrict__ att,
    const int* __restrict__ idxbuf, const float* __restrict__ wt,
    float* __restrict__ outf, int g) {
  constexpr int NCEN = 128 / NS;
  constexpr int XS = 132;
  float* red = xs;
  const int t = threadIdx.x;
  const int cid0 = bi * NCEN;
  const int b = cid0 >> 10;

  const float* w0  = wt;
  const float* w1  = wt + 67*64;
  const float* w2  = w1 + 64*64;
  const float* bb0 = w2 + 64*128;
  const float* bb1 = bb0 + 64;
  const float* bb2 = bb1 + 64;

  // ---- stage w2 (64x128) into LDS, coalesced; ordered by the barrier
  //      after the L1 epilogue (first use is in L3, two barriers later) ----
  {
    const float4* src = (const float4*)w2;
    float4* dst = (float4*)w2s;
#pragma unroll
    for (int j = 0; j < 8; ++j)
      dst[j*256 + t] = src[j*256 + t];
  }

  const int og = t & 15, cg = t >> 4;
  float acc[4][8];

  // ---- layer 1 (no LDS stage, no barrier): acc = (b0 - C1) + G1[p] ----
  {
    const int col0 = cg * 8;                 // 8 cols/thread, same center
    const int cidg = cid0 + col0 / NS;
    const int jb = cidg * NS + (col0 % NS);
    const int4 pA = *(const int4*)&idxbuf[jb];
    const int4 pB = *(const int4*)&idxbuf[jb + 4];
    int pc[8] = {pA.x, pA.y, pA.z, pA.w, pB.x, pB.y, pB.z, pB.w};
    const float nx = nxyz[cidg*3], ny = nxyz[cidg*3+1], nz = nxyz[cidg*3+2];
    const float4 bv = *(const float4*)&bb0[og*4];
    float bc[4];
#pragma unroll
    for (int j = 0; j < 4; ++j) {
      const int o = og*4 + j;
      float c1 = fmaf(w0[128+o], nz, fmaf(w0[64+o], ny, w0[o]*nx));
      bc[j] = ((const float*)&bv)[j] - c1;
    }
#pragma unroll
    for (int cc = 0; cc < 8; ++cc) {
      float4 fv = *(const float4*)&f1g[((size_t)b * N_ + pc[cc]) * 64 + og*4];
      acc[0][cc] = bc[0] + fv.x;
      acc[1][cc] = bc[1] + fv.y;
      acc[2][cc] = bc[2] + fv.z;
      acc[3][cc] = bc[3] + fv.w;
    }
  }
#pragma unroll
  for (int oo = 0; oo < 4; ++oo) {
    float4 y0, y1;
    y0.x=fmaxf(acc[oo][0],0.f); y0.y=fmaxf(acc[oo][1],0.f);
    y0.z=fmaxf(acc[oo][2],0.f); y0.w=fmaxf(acc[oo][3],0.f);
    y1.x=fmaxf(acc[oo][4],0.f); y1.y=fmaxf(acc[oo][5],0.f);
    y1.z=fmaxf(acc[oo][6],0.f); y1.w=fmaxf(acc[oo][7],0.f);
    *(float4*)&xs[(og*4+oo)*XS + cg*8]     = y0;
    *(float4*)&xs[(og*4+oo)*XS + cg*8 + 4] = y1;
  }
  __syncthreads();

  // ---- layer 2: 64 -> 64 (w1 from global/L2) ----
  {
    float4 bv = *(const float4*)&bb1[og*4];
    float b4[4] = {bv.x, bv.y, bv.z, bv.w};
#pragma unroll
    for (int oo = 0; oo < 4; ++oo)
#pragma unroll
      for (int cc = 0; cc < 8; ++cc) acc[oo][cc] = b4[oo];
#pragma unroll 2
    for (int k = 0; k < 64; ++k) {
      float4 x0 = *(const float4*)&xs[k*XS + cg*8];
      float4 x1 = *(const float4*)&xs[k*XS + cg*8 + 4];
      float4 wv = *(const float4*)&w1[k*64 + og*4];
      float x8[8] = {x0.x,x0.y,x0.z,x0.w,x1.x,x1.y,x1.z,x1.w};
      float w4[4] = {wv.x,wv.y,wv.z,wv.w};
#pragma unroll
      for (int oo = 0; oo < 4; ++oo)
#pragma unroll
        for (int cc = 0; cc < 8; ++cc) acc[oo][cc] = fmaf(w4[oo], x8[cc], acc[oo][cc]);
    }
  }
  __syncthreads();
#pragma unroll
  for (int oo = 0; oo < 4; ++oo) {
    float4 y0, y1;
    y0.x=fmaxf(acc[oo][0],0.f); y0.y=fmaxf(acc[oo][1],0.f);
    y0.z=fmaxf(acc[oo][2],0.f); y0.w=fmaxf(acc[oo][3],0.f);
    y1.x=fmaxf(acc[oo][4],0.f); y1.y=fmaxf(acc[oo][5],0.f);
    y1.z=fmaxf(acc[oo][6],0.f); y1.w=fmaxf(acc[oo][7],0.f);
    *(float4*)&xs[(og*4+oo)*XS + cg*8]     = y0;
    *(float4*)&xs[(og*4+oo)*XS + cg*8 + 4] = y1;
  }
  __syncthreads();

  // ---- layer 3: 64 -> 128 (w2 from LDS), ReLU + in-register maxpool ----
  float acc3[8][8];
  {
    float4 b0v = *(const float4*)&bb2[og*8];
    float4 b1v = *(const float4*)&bb2[og*8 + 4];
    float b8[8] = {b0v.x,b0v.y,b0v.z,b0v.w,b1v.x,b1v.y,b1v.z,b1v.w};
#pragma unroll
    for (int oo = 0; oo < 8; ++oo)
#pragma unroll
      for (int cc = 0; cc < 8; ++cc) acc3[oo][cc] = b8[oo];
#pragma unroll 2
    for (int k = 0; k < 64; ++k) {
      float4 x0 = *(const float4*)&xs[k*XS + cg*8];
      float4 x1 = *(const float4*)&xs[k*XS + cg*8 + 4];
      float4 wa = *(const float4*)&w2s[k*128 + og*8];
      float4 wb = *(const float4*)&w2s[k*128 + og*8 + 4];
      float x8[8] = {x0.x,x0.y,x0.z,x0.w,x1.x,x1.y,x1.z,x1.w};
      float w8[8] = {wa.x,wa.y,wa.z,wa.w,wb.x,wb.y,wb.z,wb.w};
#pragma unroll
      for (int oo = 0; oo < 8; ++oo)
#pragma unroll
        for (int cc = 0; cc < 8; ++cc) acc3[oo][cc] = fmaf(w8[oo], x8[cc], acc3[oo][cc]);
    }
  }
  float pm[8];
#pragma unroll
  for (int oo = 0; oo < 8; ++oo) {
    float v = fmaxf(acc3[oo][0], 0.f);
#pragma unroll
    for (int cc = 1; cc < 8; ++cc) v = fmaxf(v, fmaxf(acc3[oo][cc], 0.f));
    pm[oo] = v;
  }
#pragma unroll
  for (int oo = 0; oo < 8; ++oo) {
    pm[oo] = fmaxf(pm[oo], __shfl_xor(pm[oo], 16));
    pm[oo] = fmaxf(pm[oo], __shfl_xor(pm[oo], 32));
  }
  __syncthreads();
  if ((t & 63) < 16) {
    int w = t >> 6;
#pragma unroll
    for (int oo = 0; oo < 8; ++oo) red[w*128 + og*8 + oo] = pm[oo];
  }
  __syncthreads();

  const int ch = t & 127;
  const float a = att[b*256 + g*128 + ch];
  if (NS == 64) {
    int c = t >> 7;
    float v = fmaxf(red[(2*c)*128 + ch], red[(2*c+1)*128 + ch]);
    int s = (cid0 + c) & 1023;
    outf[((size_t)(b*256 + g*128 + ch)) * 1024 + s] = v * a;
  } else {
#pragma unroll
    for (int kk = 0; kk < 2; ++kk) {
      int c = (t >> 7) * 2 + kk;
      float v = red[c*128 + ch];
      int s = (cid0 + c) & 1023;
      outf[((size_t)(b*256 + g*128 + ch)) * 1024 + s] = v * a;
    }
  }
}

__global__ __launch_bounds__(256, 2) void mlp_kernel(
    const float* __restrict__ f1, const float* __restrict__ nxyz,
    const float* __restrict__ att, const int* __restrict__ idx0,
    const int* __restrict__ idx1, const float* __restrict__ wt,
    float* __restrict__ outf) {
  constexpr int XS = 132;
  __shared__ float xs[64 * XS];
  __shared__ float w2s[64 * 128];
  if (blockIdx.x < 4096)
    mlp_body<32>(blockIdx.x, xs, w2s, f1, nxyz, att, idx0, wt, outf, 0);
  else
    mlp_body<64>(blockIdx.x - 4096, xs, w2s, f1 + (size_t)B_*N_*64,
                 nxyz, att, idx1, wt + WT_G, outf, 1);
}

// ---------------------------------------------------------------------------
extern "C" void kernel_launch(void* const* d_in, const int* in_sizes, int n_in,
                              void* d_out, int out_size, void* d_ws, size_t ws_size,
                              hipStream_t stream) {
  const float* xyz   = (const float*)d_in[0];
  const float* feats = (const float*)d_in[1];
  const float* w_att = (const float*)d_in[2];
  const float* b_att = (const float*)d_in[3];
  const float* w00 = (const float*)d_in[4];
  const float* b00 = (const float*)d_in[5];
  const float* w01 = (const float*)d_in[6];
  const float* b01 = (const float*)d_in[7];
  const float* w02 = (const float*)d_in[8];
  const float* b02 = (const float*)d_in[9];
  const float* w10 = (const float*)d_in[10];
  const float* b10 = (const float*)d_in[11];
  const float* w11 = (const float*)d_in[12];
  const float* b11 = (const float*)d_in[13];
  const float* w12 = (const float*)d_in[14];
  const float* b12 = (const float*)d_in[15];

  float* wsf = (float*)d_ws;
  int*   wsi = (int*)d_ws;
  float4* xyzf = (float4*)(wsf + WS_XYZF);
  float* nxyz  = wsf + WS_NXYZ;
  float* att   = wsf + WS_ATT;
  float* wt    = wsf + WS_WT;
  int* idx0 = wsi + WS_IDX0;
  int* idx1 = wsi + WS_IDX1;
  float* f1 = wsf + WS_F1;

  float* out  = (float*)d_out;
  float* outf = out + B_ * S_ * 3;

  hipLaunchKernelGGL(g1_kernel, dim3(G1_BLK), dim3(256), 0, stream,
                     xyz, feats, w00, w10, f1);
  hipLaunchKernelGGL(fps_wt_kernel, dim3(B_ + WT_BLK), dim3(FPS_T), 0, stream,
                     xyz, w00, w01, w02, b00, b01, b02, w10, w11, w12,
                     b10, b11, b12, xyzf, wt, nxyz, out);
  hipLaunchKernelGGL(ballq_att_kernel, dim3(B_*S_/4 + B_), dim3(256), 0, stream,
                     xyzf, nxyz, idx0, idx1, w_att, b_att, att);
  hipLaunchKernelGGL(mlp_kernel, dim3(12288), dim3(256), 0, stream,
                     f1, nxyz, att, idx0, idx1, wt, outf);
}

// Round 17
// 1272.849 us; speedup vs baseline: 1.0373x; 1.0373x over previous
//
#include <hip/hip_runtime.h>
#include <cstdint>
#include <cstddef>

// ---------------------------------------------------------------------------
// PointNet++ SA module (multi-scale grouping) with attention gate.
// B=16, N=4096, C_IN=64, NPOINT=1024, radii (0.2,0.4), nsamples (32,64),
// MLPs ((64,64,128),(64,64,128)), C_TOTAL=256. Inputs f32, output f32.
// Round 26: champion lock-in — byte-exact revert to the round-23 config
// (measured 1278.7us, best of 16 rounds). r25's w2-LDS staging regressed
// (+40us: 65KB LDS halved blocks/CU 4->2 and added stage traffic; K3's
// stall is NOT weight-load latency). K3 ablation complete: 128col/4w=570
// BEST; 64col/6w=689; 256col/2w=572; +w2stage=610; packed-f32 neutral.
// FPS ablation complete: 512thr/8w + key-only winner + sx-broadcast = 587
// BEST (256=913, 1024=936, dual-batch 1686, DPP-tail 858, readlane 822).
// K3 model: ~280us VALU issue + ~264us LDS b128 throughput, partially
// serialized by per-k deps — remaining levers are numerics-changing.
// ---------------------------------------------------------------------------

constexpr int B_ = 16, N_ = 4096, S_ = 1024;
constexpr int WT_G = 67*64 + 64*64 + 128*64 + 64 + 64 + 128; // 16832 floats/group
constexpr int FPS_T = 512;                                   // threads per FPS block
constexpr int WT_BLK = (2*WT_G + FPS_T - 1) / FPS_T;         // 66
constexpr int G1_BLK = 2 * B_ * (N_ / 128);                  // 1024

// workspace layout in 4-byte units
constexpr int WS_XYZF = 0;                       // float4[B*N]
constexpr int WS_NXYZ = B_*N_*4;                 // float[B*S*3]
constexpr int WS_ATT  = WS_NXYZ + B_*S_*3;       // float[B*256]
constexpr int WS_WT   = WS_ATT + B_*256;         // float[2*WT_G]
constexpr int WS_IDX0 = WS_WT + 2*WT_G;          // int[B*S*32]
constexpr int WS_IDX1 = WS_IDX0 + B_*S_*32;      // int[B*S*64]
constexpr int WS_F1   = WS_IDX1 + B_*S_*64;      // float[2*B*N*64] G1 values

// ---------------------------------------------------------------------------
// K0: G1 precompute. Per point p: G1[o] = sum_c w0[o,c]*in[c], in=(xyz,feat).
// 1024 blocks x 256 thr; 2 threads/point, 32 outs each (4 waves/SIMD).
// Per-out accumulation order identical to the original layer-1 k-loop.
// ---------------------------------------------------------------------------
__global__ __launch_bounds__(256) void g1_kernel(
    const float* __restrict__ xyz, const float* __restrict__ feats,
    const float* __restrict__ w00, const float* __restrict__ w10,
    float* __restrict__ f1) {
  __shared__ float wfs[67 * 64];   // wfs[c*64+o] = w[o*67+c]
  const int fid = blockIdx.x;                     // 0..1023
  const int g = fid >> 9, b = (fid >> 5) & 15, chunk = fid & 31;
  const float* w = g ? w10 : w00;
  for (int k = threadIdx.x; k < 67*64; k += 256) {
    int c = k >> 6, o = k & 63;
    wfs[k] = w[o*67 + c];
  }
  __syncthreads();
  const int p = chunk * 128 + (threadIdx.x >> 1);
  const int half = (threadIdx.x & 1) * 32;        // output half: o = half..half+31
  const float* xr = xyz + ((size_t)b * N_ + p) * 3;
  const float* fr = feats + ((size_t)b * N_ + p) * 64;
  float acc[32];
  {
    float x0 = xr[0], x1 = xr[1], x2 = xr[2];
#pragma unroll
    for (int j = 0; j < 32; j += 4) {
      float4 wA = *(const float4*)&wfs[0*64 + half + j];
      acc[j+0] = wA.x * x0; acc[j+1] = wA.y * x0;
      acc[j+2] = wA.z * x0; acc[j+3] = wA.w * x0;
    }
#pragma unroll
    for (int j = 0; j < 32; j += 4) {
      float4 wA = *(const float4*)&wfs[1*64 + half + j];
      acc[j+0] = fmaf(wA.x, x1, acc[j+0]); acc[j+1] = fmaf(wA.y, x1, acc[j+1]);
      acc[j+2] = fmaf(wA.z, x1, acc[j+2]); acc[j+3] = fmaf(wA.w, x1, acc[j+3]);
    }
#pragma unroll
    for (int j = 0; j < 32; j += 4) {
      float4 wA = *(const float4*)&wfs[2*64 + half + j];
      acc[j+0] = fmaf(wA.x, x2, acc[j+0]); acc[j+1] = fmaf(wA.y, x2, acc[j+1]);
      acc[j+2] = fmaf(wA.z, x2, acc[j+2]); acc[j+3] = fmaf(wA.w, x2, acc[j+3]);
    }
  }
  for (int c = 0; c < 64; ++c) {
    float v = fr[c];
    const float* wr = &wfs[(3 + c) * 64 + half];
#pragma unroll
    for (int j = 0; j < 32; j += 4) {
      float4 w4 = *(const float4*)&wr[j];
      acc[j+0] = fmaf(w4.x, v, acc[j+0]); acc[j+1] = fmaf(w4.y, v, acc[j+1]);
      acc[j+2] = fmaf(w4.z, v, acc[j+2]); acc[j+3] = fmaf(w4.w, v, acc[j+3]);
    }
  }
  float* op = f1 + (((size_t)g * B_ + b) * N_ + p) * 64 + half;
#pragma unroll
  for (int j = 0; j < 32; j += 4) {
    float4 r = make_float4(acc[j], acc[j+1], acc[j+2], acc[j+3]);
    *(float4*)&op[j] = r;
  }
}

// ---------------------------------------------------------------------------
// K1: FPS (blocks 0..15, 512 thr / 8 waves / PPT=8) + weight transpose
// (blocks 16..81). Byte-identical to r21 (587 us measured).
// ---------------------------------------------------------------------------
__global__ __launch_bounds__(512) void fps_wt_kernel(
    const float* __restrict__ xyz,
    const float* __restrict__ w00, const float* __restrict__ w01,
    const float* __restrict__ w02, const float* __restrict__ b00,
    const float* __restrict__ b01, const float* __restrict__ b02,
    const float* __restrict__ w10, const float* __restrict__ w11,
    const float* __restrict__ w12, const float* __restrict__ b10,
    const float* __restrict__ b11, const float* __restrict__ b12,
    float4* __restrict__ xyzf, float* __restrict__ wt,
    float* __restrict__ nxyz, float* __restrict__ out_nxyz) {
  constexpr int PPT = 8;           // points per thread (4096 / 512)
  __shared__ float sx[N_*3];
  __shared__ int   selidx[S_];
  __shared__ alignas(16) unsigned long long redP[2][8];

  if (blockIdx.x >= B_) {
    // ---- weight-transpose role (runs on idle CUs during FPS) ----
    int wid = (blockIdx.x - B_) * FPS_T + threadIdx.x;
    if (wid >= 2*WT_G) return;
    int g = wid / WT_G, r = wid % WT_G;
    float val;
    if (r < 4288) {                    // layer0: w (64,67) -> wt0[c*64+o]
      int c = r >> 6, o = r & 63;
      val = (g ? w10 : w00)[o*67 + c];
    } else if (r < 8384) {             // layer1: w (64,64) -> wt1[c*64+o]
      int rr = r - 4288; int c = rr >> 6, o = rr & 63;
      val = (g ? w11 : w01)[o*64 + c];
    } else if (r < 16576) {            // layer2: w (128,64) -> wt2[c*128+o]
      int rr = r - 8384; int c = rr >> 7, o = rr & 127;
      val = (g ? w12 : w02)[o*64 + c];
    } else {                           // biases
      int rr = r - 16576;
      val = (rr < 64)  ? (g ? b10 : b00)[rr]
          : (rr < 128) ? (g ? b11 : b01)[rr - 64]
                       : (g ? b12 : b02)[rr - 128];
    }
    wt[g*WT_G + r] = val;
    return;
  }

  // ---- FPS role ----
  const int b = blockIdx.x, t = threadIdx.x;
  const int wv = t >> 6;  // wave id 0..7
  const float* xr = xyz + (size_t)b * N_ * 3;
  for (int k = t; k < N_*3; k += FPS_T) sx[k] = xr[k];   // coalesced stage
  if (t == 0) selidx[0] = 0;   // first sampled index is 0 (matches reference)
  __syncthreads();
  float px[PPT], py[PPT], pz[PPT], m[PPT];
#pragma unroll
  for (int p = 0; p < PPT; ++p) {
    int idx = t * PPT + p;
    px[p] = sx[idx*3+0]; py[p] = sx[idx*3+1]; pz[p] = sx[idx*3+2];
    m[p] = 1e10f;
  }
  float lx = sx[0], ly = sx[1], lz = sx[2];
  for (int i = 1; i < S_; ++i) {
    // ---- distance + running-min update (bit-exact np arithmetic) ----
#pragma unroll
    for (int p = 0; p < PPT; ++p) {
      float dx = __fsub_rn(px[p], lx), dy = __fsub_rn(py[p], ly), dz = __fsub_rn(pz[p], lz);
      float d = __fadd_rn(__fadd_rn(__fmul_rn(dx,dx), __fmul_rn(dy,dy)), __fmul_rn(dz,dz));
      m[p] = fminf(m[p], d);
    }
    // ---- local argmax: max tree + reverse == scan (smallest p wins) ----
    float h0 = fmaxf(fmaxf(m[0], m[1]), fmaxf(m[2], m[3]));
    float h1 = fmaxf(fmaxf(m[4], m[5]), fmaxf(m[6], m[7]));
    float bv = fmaxf(h0, h1);
    int bp = PPT - 1;
#pragma unroll
    for (int p = PPT - 2; p >= 0; --p)
      if (m[p] == bv) bp = p;           // ends at smallest p attaining bv
    const int bi = t * PPT + bp;
    // ---- wave max via DPP (uint compare valid: all m >= 0, no NaN) ----
    unsigned vm = __float_as_uint(bv);
#define DPP_MAX(ctrl) { unsigned o = (unsigned)__builtin_amdgcn_update_dpp((int)vm, (int)vm, (ctrl), 0xf, 0xf, false); vm = vm > o ? vm : o; }
    DPP_MAX(0x111)  // row_shr:1
    DPP_MAX(0x112)  // row_shr:2
    DPP_MAX(0x114)  // row_shr:4
    DPP_MAX(0x118)  // row_shr:8
    DPP_MAX(0x142)  // row_bcast:15
    DPP_MAX(0x143)  // row_bcast:31
#undef DPP_MAX
    const unsigned wmaxu = (unsigned)__builtin_amdgcn_readlane((int)vm, 63);
    // smallest index attaining the wave max: lanes are index-ordered
    const unsigned long long mk = __ballot(__float_as_uint(bv) == wmaxu);
    const int fl = (int)__builtin_ctzll(mk);
    const int widx = __builtin_amdgcn_readlane(bi, fl);
    const int par = i & 1;
    // ---- winner lane forwards packed key ONLY (no coord select/write) ----
    if (t == (widx >> 3))
      redP[par][wv] = ((unsigned long long)wmaxu << 32) | (unsigned)(~widx);
    __syncthreads();
    // ---- all threads: combine 8 wave candidates (broadcast LDS reads),
    //      then fetch winner coords straight from sx (uniform broadcast) ----
    ulonglong2 pA = *(const ulonglong2*)&redP[par][0];
    ulonglong2 pB = *(const ulonglong2*)&redP[par][2];
    ulonglong2 pC = *(const ulonglong2*)&redP[par][4];
    ulonglong2 pD = *(const ulonglong2*)&redP[par][6];
    unsigned long long q0 = pA.x > pA.y ? pA.x : pA.y;
    unsigned long long q1 = pB.x > pB.y ? pB.x : pB.y;
    unsigned long long q2 = pC.x > pC.y ? pC.x : pC.y;
    unsigned long long q3 = pD.x > pD.y ? pD.x : pD.y;
    unsigned long long r0 = q0 > q1 ? q0 : q1;
    unsigned long long r1 = q2 > q3 ? q2 : q3;
    unsigned long long win = r0 > r1 ? r0 : r1;
    const int fi = (int)(~(unsigned)win);   // global index of selected point
    lx = sx[fi*3+0]; ly = sx[fi*3+1]; lz = sx[fi*3+2];  // broadcast reads
    if (t == 0) selidx[i] = fi;
  }
  __syncthreads();
  // epilogue: coalesced write of new_xyz (ws + out) and xyzf (float4-padded)
  for (int k = t; k < S_; k += FPS_T) {
    int id = selidx[k];
    float x = sx[id*3], y = sx[id*3+1], z = sx[id*3+2];
    int o = (b * S_ + k) * 3;
    nxyz[o] = x; nxyz[o+1] = y; nxyz[o+2] = z;
    out_nxyz[o] = x; out_nxyz[o+1] = y; out_nxyz[o+2] = z;
  }
  for (int k = t; k < N_; k += FPS_T) {
    float4 v; v.x = sx[k*3]; v.y = sx[k*3+1]; v.z = sx[k*3+2]; v.w = 0.f;
    xyzf[b * N_ + k] = v;
  }
}

// ---------------------------------------------------------------------------
// K2: fused dual-radius ball query (blocks 0..4095) + attention gate
// (blocks 4096..4111). Byte-identical to round 9.
// ---------------------------------------------------------------------------
__global__ __launch_bounds__(256) void ballq_att_kernel(
    const float4* __restrict__ xyzf, const float* __restrict__ nxyz,
    int* __restrict__ idx0buf, int* __restrict__ idx1buf,
    const float* __restrict__ w_att, const float* __restrict__ b_att,
    float* __restrict__ att) {
  __shared__ float ai[3 * S_];
  if (blockIdx.x >= B_*S_/4) {
    // ---- attention role ----
    int b = blockIdx.x - B_*S_/4, t = threadIdx.x;
    for (int k = t; k < 3 * S_; k += 256) {
      int d = k >> 10, s = k & 1023;
      ai[k] = nxyz[(b * S_ + s) * 3 + d];
    }
    __syncthreads();
    float acc = b_att[t];
#pragma unroll 8
    for (int k = 0; k < 3 * S_; ++k)
      acc = fmaf(ai[k], w_att[k * 256 + t], acc);
    att[b * 256 + t] = 1.f / (1.f + expf(-acc));
    return;
  }
  // ---- ball-query role ----
  const float r2a = (float)(0.2 * 0.2), r2b = (float)(0.4 * 0.4);
  int lane = threadIdx.x & 63;
  int cid = blockIdx.x * 4 + (threadIdx.x >> 6);
  int b = cid >> 10;
  float cx = nxyz[cid*3], cy = nxyz[cid*3+1], cz = nxyz[cid*3+2];
  const float4* xb = xyzf + b * N_;
  int cnt0 = 0, cnt1 = 0, first0 = 0, first1 = 0;
  const unsigned long long below = (1ull << lane) - 1ull;
  for (int base = 0; base < N_; base += 64) {
    float4 P = xb[base + lane];
    float dx = __fsub_rn(cx, P.x), dy = __fsub_rn(cy, P.y), dz = __fsub_rn(cz, P.z);
    float d2 = __fadd_rn(__fadd_rn(__fmul_rn(dx,dx), __fmul_rn(dy,dy)), __fmul_rn(dz,dz));
    bool h0 = d2 < r2a, h1 = d2 < r2b;
    unsigned long long m0 = __ballot(h0), m1 = __ballot(h1);
    if (cnt0 == 0 && m0 != 0ull) first0 = base + (int)__builtin_ctzll(m0);
    if (cnt1 == 0 && m1 != 0ull) first1 = base + (int)__builtin_ctzll(m1);
    if (h0) {
      int pos = cnt0 + (int)__popcll(m0 & below);
      if (pos < 32) idx0buf[cid * 32 + pos] = base + lane;
    }
    if (h1) {
      int pos = cnt1 + (int)__popcll(m1 & below);
      if (pos < 64) idx1buf[cid * 64 + pos] = base + lane;
    }
    cnt0 += (int)__popcll(m0);
    cnt1 += (int)__popcll(m1);
    if (cnt0 >= 32 && cnt1 >= 64) break;
  }
  if (cnt0 < 32)
    for (int p = cnt0 + lane; p < 32; p += 64) idx0buf[cid * 32 + p] = first0;
  if (cnt1 < 64)
    for (int p = cnt1 + lane; p < 64; p += 64) idx1buf[cid * 64 + p] = first1;
}

// ---------------------------------------------------------------------------
// K3: GEMM-tiled fused MLP + maxpool + attention + store. Byte-identical to
// r18 (128 cols/block, de-staged layer 1, scalar fmaf, unroll-2 k-loops).
// ---------------------------------------------------------------------------
template<int NS>
__device__ __forceinline__ void mlp_body(int bi, float* xs,
    const float* __restrict__ f1g,
    const float* __restrict__ nxyz, const float* __restrict__ att,
    const int* __restrict__ idxbuf, const float* __restrict__ wt,
    float* __restrict__ outf, int g) {
  constexpr int NCEN = 128 / NS;
  constexpr int XS = 132;
  float* red = xs;
  const int t = threadIdx.x;
  const int cid0 = bi * NCEN;
  const int b = cid0 >> 10;

  const float* w0  = wt;
  const float* w1  = wt + 67*64;
  const float* w2  = w1 + 64*64;
  const float* bb0 = w2 + 64*128;
  const float* bb1 = bb0 + 64;
  const float* bb2 = bb1 + 64;

  const int og = t & 15, cg = t >> 4;
  float acc[4][8];

  // ---- layer 1 (no LDS stage, no barrier): acc = (b0 - C1) + G1[p] ----
  {
    const int col0 = cg * 8;                 // 8 cols/thread, same center
    const int cidg = cid0 + col0 / NS;
    const int jb = cidg * NS + (col0 % NS);
    const int4 pA = *(const int4*)&idxbuf[jb];
    const int4 pB = *(const int4*)&idxbuf[jb + 4];
    int pc[8] = {pA.x, pA.y, pA.z, pA.w, pB.x, pB.y, pB.z, pB.w};
    const float nx = nxyz[cidg*3], ny = nxyz[cidg*3+1], nz = nxyz[cidg*3+2];
    const float4 bv = *(const float4*)&bb0[og*4];
    float bc[4];
#pragma unroll
    for (int j = 0; j < 4; ++j) {
      const int o = og*4 + j;
      float c1 = fmaf(w0[128+o], nz, fmaf(w0[64+o], ny, w0[o]*nx));
      bc[j] = ((const float*)&bv)[j] - c1;
    }
#pragma unroll
    for (int cc = 0; cc < 8; ++cc) {
      float4 fv = *(const float4*)&f1g[((size_t)b * N_ + pc[cc]) * 64 + og*4];
      acc[0][cc] = bc[0] + fv.x;
      acc[1][cc] = bc[1] + fv.y;
      acc[2][cc] = bc[2] + fv.z;
      acc[3][cc] = bc[3] + fv.w;
    }
  }
#pragma unroll
  for (int oo = 0; oo < 4; ++oo) {
    float4 y0, y1;
    y0.x=fmaxf(acc[oo][0],0.f); y0.y=fmaxf(acc[oo][1],0.f);
    y0.z=fmaxf(acc[oo][2],0.f); y0.w=fmaxf(acc[oo][3],0.f);
    y1.x=fmaxf(acc[oo][4],0.f); y1.y=fmaxf(acc[oo][5],0.f);
    y1.z=fmaxf(acc[oo][6],0.f); y1.w=fmaxf(acc[oo][7],0.f);
    *(float4*)&xs[(og*4+oo)*XS + cg*8]     = y0;
    *(float4*)&xs[(og*4+oo)*XS + cg*8 + 4] = y1;
  }
  __syncthreads();

  // ---- layer 2: 64 -> 64 ----
  {
    float4 bv = *(const float4*)&bb1[og*4];
    float b4[4] = {bv.x, bv.y, bv.z, bv.w};
#pragma unroll
    for (int oo = 0; oo < 4; ++oo)
#pragma unroll
      for (int cc = 0; cc < 8; ++cc) acc[oo][cc] = b4[oo];
#pragma unroll 2
    for (int k = 0; k < 64; ++k) {
      float4 x0 = *(const float4*)&xs[k*XS + cg*8];
      float4 x1 = *(const float4*)&xs[k*XS + cg*8 + 4];
      float4 wv = *(const float4*)&w1[k*64 + og*4];
      float x8[8] = {x0.x,x0.y,x0.z,x0.w,x1.x,x1.y,x1.z,x1.w};
      float w4[4] = {wv.x,wv.y,wv.z,wv.w};
#pragma unroll
      for (int oo = 0; oo < 4; ++oo)
#pragma unroll
        for (int cc = 0; cc < 8; ++cc) acc[oo][cc] = fmaf(w4[oo], x8[cc], acc[oo][cc]);
    }
  }
  __syncthreads();
#pragma unroll
  for (int oo = 0; oo < 4; ++oo) {
    float4 y0, y1;
    y0.x=fmaxf(acc[oo][0],0.f); y0.y=fmaxf(acc[oo][1],0.f);
    y0.z=fmaxf(acc[oo][2],0.f); y0.w=fmaxf(acc[oo][3],0.f);
    y1.x=fmaxf(acc[oo][4],0.f); y1.y=fmaxf(acc[oo][5],0.f);
    y1.z=fmaxf(acc[oo][6],0.f); y1.w=fmaxf(acc[oo][7],0.f);
    *(float4*)&xs[(og*4+oo)*XS + cg*8]     = y0;
    *(float4*)&xs[(og*4+oo)*XS + cg*8 + 4] = y1;
  }
  __syncthreads();

  // ---- layer 3: 64 -> 128, ReLU + in-register partial maxpool ----
  float acc3[8][8];
  {
    float4 b0v = *(const float4*)&bb2[og*8];
    float4 b1v = *(const float4*)&bb2[og*8 + 4];
    float b8[8] = {b0v.x,b0v.y,b0v.z,b0v.w,b1v.x,b1v.y,b1v.z,b1v.w};
#pragma unroll
    for (int oo = 0; oo < 8; ++oo)
#pragma unroll
      for (int cc = 0; cc < 8; ++cc) acc3[oo][cc] = b8[oo];
#pragma unroll 2
    for (int k = 0; k < 64; ++k) {
      float4 x0 = *(const float4*)&xs[k*XS + cg*8];
      float4 x1 = *(const float4*)&xs[k*XS + cg*8 + 4];
      float4 wa = *(const float4*)&w2[k*128 + og*8];
      float4 wb = *(const float4*)&w2[k*128 + og*8 + 4];
      float x8[8] = {x0.x,x0.y,x0.z,x0.w,x1.x,x1.y,x1.z,x1.w};
      float w8[8] = {wa.x,wa.y,wa.z,wa.w,wb.x,wb.y,wb.z,wb.w};
#pragma unroll
      for (int oo = 0; oo < 8; ++oo)
#pragma unroll
        for (int cc = 0; cc < 8; ++cc) acc3[oo][cc] = fmaf(w8[oo], x8[cc], acc3[oo][cc]);
    }
  }
  float pm[8];
#pragma unroll
  for (int oo = 0; oo < 8; ++oo) {
    float v = fmaxf(acc3[oo][0], 0.f);
#pragma unroll
    for (int cc = 1; cc < 8; ++cc) v = fmaxf(v, fmaxf(acc3[oo][cc], 0.f));
    pm[oo] = v;
  }
#pragma unroll
  for (int oo = 0; oo < 8; ++oo) {
    pm[oo] = fmaxf(pm[oo], __shfl_xor(pm[oo], 16));
    pm[oo] = fmaxf(pm[oo], __shfl_xor(pm[oo], 32));
  }
  __syncthreads();
  if ((t & 63) < 16) {
    int w = t >> 6;
#pragma unroll
    for (int oo = 0; oo < 8; ++oo) red[w*128 + og*8 + oo] = pm[oo];
  }
  __syncthreads();

  const int ch = t & 127;
  const float a = att[b*256 + g*128 + ch];
  if (NS == 64) {
    int c = t >> 7;
    float v = fmaxf(red[(2*c)*128 + ch], red[(2*c+1)*128 + ch]);
    int s = (cid0 + c) & 1023;
    outf[((size_t)(b*256 + g*128 + ch)) * 1024 + s] = v * a;
  } else {
#pragma unroll
    for (int kk = 0; kk < 2; ++kk) {
      int c = (t >> 7) * 2 + kk;
      float v = red[c*128 + ch];
      int s = (cid0 + c) & 1023;
      outf[((size_t)(b*256 + g*128 + ch)) * 1024 + s] = v * a;
    }
  }
}

__global__ __launch_bounds__(256, 4) void mlp_kernel(
    const float* __restrict__ f1, const float* __restrict__ nxyz,
    const float* __restrict__ att, const int* __restrict__ idx0,
    const int* __restrict__ idx1, const float* __restrict__ wt,
    float* __restrict__ outf) {
  constexpr int XS = 132;
  __shared__ float xs[64 * XS];
  if (blockIdx.x < 4096)
    mlp_body<32>(blockIdx.x, xs, f1, nxyz, att, idx0, wt, outf, 0);
  else
    mlp_body<64>(blockIdx.x - 4096, xs, f1 + (size_t)B_*N_*64,
                 nxyz, att, idx1, wt + WT_G, outf, 1);
}

// ---------------------------------------------------------------------------
extern "C" void kernel_launch(void* const* d_in, const int* in_sizes, int n_in,
                              void* d_out, int out_size, void* d_ws, size_t ws_size,
                              hipStream_t stream) {
  const float* xyz   = (const float*)d_in[0];
  const float* feats = (const float*)d_in[1];
  const float* w_att = (const float*)d_in[2];
  const float* b_att = (const float*)d_in[3];
  const float* w00 = (const float*)d_in[4];
  const float* b00 = (const float*)d_in[5];
  const float* w01 = (const float*)d_in[6];
  const float* b01 = (const float*)d_in[7];
  const float* w02 = (const float*)d_in[8];
  const float* b02 = (const float*)d_in[9];
  const float* w10 = (const float*)d_in[10];
  const float* b10 = (const float*)d_in[11];
  const float* w11 = (const float*)d_in[12];
  const float* b11 = (const float*)d_in[13];
  const float* w12 = (const float*)d_in[14];
  const float* b12 = (const float*)d_in[15];

  float* wsf = (float*)d_ws;
  int*   wsi = (int*)d_ws;
  float4* xyzf = (float4*)(wsf + WS_XYZF);
  float* nxyz  = wsf + WS_NXYZ;
  float* att   = wsf + WS_ATT;
  float* wt    = wsf + WS_WT;
  int* idx0 = wsi + WS_IDX0;
  int* idx1 = wsi + WS_IDX1;
  float* f1 = wsf + WS_F1;

  float* out  = (float*)d_out;
  float* outf = out + B_ * S_ * 3;

  hipLaunchKernelGGL(g1_kernel, dim3(G1_BLK), dim3(256), 0, stream,
                     xyz, feats, w00, w10, f1);
  hipLaunchKernelGGL(fps_wt_kernel, dim3(B_ + WT_BLK), dim3(FPS_T), 0, stream,
                     xyz, w00, w01, w02, b00, b01, b02, w10, w11, w12,
                     b10, b11, b12, xyzf, wt, nxyz, out);
  hipLaunchKernelGGL(ballq_att_kernel, dim3(B_*S_/4 + B_), dim3(256), 0, stream,
                     xyzf, nxyz, idx0, idx1, w_att, b_att, att);
  hipLaunchKernelGGL(mlp_kernel, dim3(12288), dim3(256), 0, stream,
                     f1, nxyz, att, idx0, idx1, wt, outf);
}